// Round 6
// baseline (393.261 us; speedup 1.0000x reference)
//
#include <hip/hip_runtime.h>
#include <hip/hip_bf16.h>
#include <cstdint>
#include <cstddef>

// Problem constants (fixed shapes per reference)
#define NROWS 8192
#define DIM   1024
#define TW    64          // per-wave output tile: 64x64
#define BK    32          // K depth per MFMA step
#define NITER (DIM / BK)  // 32
#define NTILE (NROWS / TW)              // 128
#define NTRI  (NTILE * (NTILE + 1) / 2) // 8256 tiles, 4 waves/block -> 2064 blocks
#define INV_T 10.0f
#define EPS 1e-8f

typedef short  bf16x8  __attribute__((ext_vector_type(8)));
typedef float  floatx4 __attribute__((ext_vector_type(4)));

__device__ __forceinline__ unsigned short f2bf_rne(float f) {
    union { float f; unsigned u; } c; c.f = f;
    unsigned u = c.u;
    unsigned r = (u + 0x7fffu + ((u >> 16) & 1u)) >> 16;
    return (unsigned short)r;
}

// ---------------------------------------------------------------------------
// Kernel A: fp32 -> bf16 (RNE), vectorized. First 64 blocks also zero the
// 16384-float accumulator region (replaces a separate memset dispatch).
// ---------------------------------------------------------------------------
__global__ __launch_bounds__(256) void convert_kernel(
    const float* __restrict__ in, unsigned short* __restrict__ out,
    float* __restrict__ accum /* all_sum ++ pos_sum, 2*NROWS floats */)
{
    int i = (blockIdx.x * 256 + threadIdx.x) * 4;
    float4 v = *(const float4*)(in + i);
    ushort4 o;
    o.x = f2bf_rne(v.x);
    o.y = f2bf_rne(v.y);
    o.z = f2bf_rne(v.z);
    o.w = f2bf_rne(v.w);
    *(ushort4*)(out + i) = o;
    if (blockIdx.x < (2 * NROWS) / 256)
        accum[blockIdx.x * 256 + threadIdx.x] = 0.0f;
}

// ---------------------------------------------------------------------------
// Kernel B: barrier-free symmetric-half fused GEMM.
// One wave = one 64x64 tile; NO LDS, NO __syncthreads in the entire kernel.
// Both MFMA operands are rows of E with contiguous K, so fragments load
// directly global->VGPR as dwordx4 (A-layout: m=lane&15, k=quad*8+j). A wave's
// fragment load covers 16 rows x 64B full cache lines (lanes c,c+16,c+32,c+48
// read consecutive 16B of row c). Double-buffered register fragments + fully
// unrolled K-loop (immediate offsets 0..1984B) let the compiler interleave
// MFMA with loads under fine-grained vmcnt — no barrier ever drains vmcnt(0).
// Off-diagonal tiles feed row- AND col-reduces (symmetry); diag masks j==i.
// XCD swizzle: block b -> tile chunk (b%8)*258 + b/8, so each XCD works
// contiguous bi-strips (A-row L2 locality); 4 waves/block take 4 consecutive
// tiles (shared A rows -> L1 hits).
// ---------------------------------------------------------------------------
__global__ __launch_bounds__(256, 3) void gemm_fused_kernel(
    const unsigned short* __restrict__ E,   // bf16 bits, row-major [NROWS][DIM]
    const int*            __restrict__ labels,
    float*                __restrict__ all_sum,
    float*                __restrict__ pos_sum)
{
    const int tid  = threadIdx.x;
    const int lane = tid & 63;
    const int w    = tid >> 6;
    const int colw = lane & 15;
    const int quad = lane >> 4;

    // XCD-swizzled tile id: 2064 blocks = 8 XCDs x 258; wave w takes tile +w.
    const int b    = blockIdx.x;
    const int t    = ((b & 7) * 258 + (b >> 3)) * 4 + w;

    // decode lower-triangle pair: t -> (bi, bj), bj <= bi  (64-granular tiles)
    int bi = (int)((sqrtf(8.0f * (float)t + 1.0f) - 1.0f) * 0.5f);
    while ((bi + 1) * (bi + 2) / 2 <= t) ++bi;
    while (bi * (bi + 1) / 2 > t) --bi;
    const int bj = t - bi * (bi + 1) / 2;

    const int rBase = bi * TW;      // rows (A side)
    const int cBase = bj * TW;      // cols (B side)
    const bool diag = (bi == bj);

    // Fragment base pointers: row = base + ft*16 + colw, k-part = quad*8.
    // All 32 K-steps reachable via immediate offsets (step = 64B, max 1984B).
    const unsigned short* aP[4];
    const unsigned short* bP[4];
    #pragma unroll
    for (int ft = 0; ft < 4; ++ft) {
        aP[ft] = E + (size_t)(rBase + ft * 16 + colw) * DIM + quad * 8;
        bP[ft] = E + (size_t)(cBase + ft * 16 + colw) * DIM + quad * 8;
    }

    floatx4 acc[4][4];
    #pragma unroll
    for (int i = 0; i < 4; ++i)
        #pragma unroll
        for (int j = 0; j < 4; ++j)
            acc[i][j] = (floatx4)0.0f;

    bf16x8 fa[2][4], fb[2][4];
    #pragma unroll
    for (int ft = 0; ft < 4; ++ft) {
        fa[0][ft] = *(const bf16x8*)(aP[ft]);
        fb[0][ft] = *(const bf16x8*)(bP[ft]);
    }

    #pragma unroll
    for (int it = 0; it < NITER; ++it) {
        const int cur = it & 1;
        const int nxt = cur ^ 1;
        if (it + 1 < NITER) {
            const int ko = (it + 1) * BK;
            #pragma unroll
            for (int ft = 0; ft < 4; ++ft) {
                fa[nxt][ft] = *(const bf16x8*)(aP[ft] + ko);
                fb[nxt][ft] = *(const bf16x8*)(bP[ft] + ko);
            }
        }
        #pragma unroll
        for (int mt = 0; mt < 4; ++mt)
            #pragma unroll
            for (int nt = 0; nt < 4; ++nt)
                acc[mt][nt] = __builtin_amdgcn_mfma_f32_16x16x32_bf16(
                    fa[cur][mt], fb[cur][nt], acc[mt][nt], 0, 0, 0);
    }

    // Epilogue. C/D layout (16x16x32): col = lane&15, row = quad*4 + reg.
    float labc[4];
    int   gcol[4];
    #pragma unroll
    for (int nt = 0; nt < 4; ++nt) {
        gcol[nt] = cBase + nt * 16 + colw;
        labc[nt] = (float)labels[gcol[nt]];
    }

    float colAll[4] = {0.f, 0.f, 0.f, 0.f};
    float colPos[4] = {0.f, 0.f, 0.f, 0.f};

    #pragma unroll
    for (int mt = 0; mt < 4; ++mt) {
        const int growBase = rBase + mt * 16 + quad * 4;
        #pragma unroll
        for (int r = 0; r < 4; ++r) {
            const int grow = growBase + r;
            const float labr = (float)labels[grow];
            float sAll = 0.f, sPos = 0.f;
            #pragma unroll
            for (int nt = 0; nt < 4; ++nt) {
                float ev = __expf(acc[mt][nt][r] * INV_T);
                if (diag && grow == gcol[nt]) ev = 0.0f;  // exclude self
                sAll += ev;
                sPos += ev * labc[nt];
                colAll[nt] += ev;
                colPos[nt] += ev * labr;
            }
            // row-reduce across the 16 lanes (same quad) sharing this row
            #pragma unroll
            for (int off = 1; off < 16; off <<= 1) {
                sAll += __shfl_xor(sAll, off);
                sPos += __shfl_xor(sPos, off);
            }
            if (colw == 0) {
                atomicAdd(&all_sum[grow], sAll);
                atomicAdd(&pos_sum[grow], sPos);
            }
        }
    }

    if (!diag) {
        // col-reduce: sum across quads (lanes differing in bits 4,5)
        #pragma unroll
        for (int nt = 0; nt < 4; ++nt) {
            float a = colAll[nt], p = colPos[nt];
            a += __shfl_xor(a, 16);  p += __shfl_xor(p, 16);
            a += __shfl_xor(a, 32);  p += __shfl_xor(p, 32);
            if (quad == 0) {
                atomicAdd(&all_sum[gcol[nt]], a);
                atomicAdd(&pos_sum[gcol[nt]], p);
            }
        }
    }
}

// ---------------------------------------------------------------------------
// Kernel C: loss = mean over rows with lab==1 of -log(pos/(all+eps)); 0 if n_ref<2
// ---------------------------------------------------------------------------
__global__ __launch_bounds__(1024) void finalize_kernel(
    const float* __restrict__ all_sum,
    const float* __restrict__ pos_sum,
    const int*   __restrict__ labels,
    float*       __restrict__ out)
{
    __shared__ float sSum[1024];
    __shared__ float sCnt[1024];
    const int tid = threadIdx.x;
    float lsum = 0.f, lcnt = 0.f;
    for (int i = tid; i < NROWS; i += 1024) {
        if (labels[i] > 0) {
            float p = pos_sum[i];
            float a = all_sum[i] + EPS;
            lsum += -logf(p / a);
            lcnt += 1.0f;
        }
    }
    sSum[tid] = lsum;
    sCnt[tid] = lcnt;
    __syncthreads();
    for (int s = 512; s > 0; s >>= 1) {
        if (tid < s) { sSum[tid] += sSum[tid + s]; sCnt[tid] += sCnt[tid + s]; }
        __syncthreads();
    }
    if (tid == 0) {
        float n = sCnt[0];
        out[0] = (n < 2.0f) ? 0.0f : sSum[0] / fmaxf(n, 1.0f);
    }
}

// ---------------------------------------------------------------------------
extern "C" void kernel_launch(void* const* d_in, const int* in_sizes, int n_in,
                              void* d_out, int out_size, void* d_ws, size_t ws_size,
                              hipStream_t stream) {
    const float* emb    = (const float*)d_in[0];
    const int*   labels = (const int*)d_in[1];
    float*       out    = (float*)d_out;

    // workspace layout: [bf16 E: 16 MB][all_sum: 32 KB][pos_sum: 32 KB]
    unsigned short* Ebf = (unsigned short*)d_ws;
    const size_t embBytes = (size_t)NROWS * DIM * sizeof(unsigned short);
    float* all_sum = (float*)((char*)d_ws + embBytes);
    float* pos_sum = all_sum + NROWS;

    convert_kernel<<<(NROWS * DIM) / (4 * 256), 256, 0, stream>>>(emb, Ebf, all_sum);

    gemm_fused_kernel<<<NTRI / 4, 256, 0, stream>>>(Ebf, labels, all_sum, pos_sum);

    finalize_kernel<<<1, 1024, 0, stream>>>(all_sum, pos_sum, labels, out);
}

// Round 7
// 213.924 us; speedup vs baseline: 1.8383x; 1.8383x over previous
//
#include <hip/hip_runtime.h>
#include <hip/hip_bf16.h>
#include <cstdint>
#include <cstddef>

// Problem constants (fixed shapes per reference)
#define NROWS 8192
#define DIM   1024
#define BM 128
#define BN 128
#define BK 64             // K depth per iteration; 16 iterations total
#define NITER (DIM / BK)
#define EPS 1e-8f
// E is pre-scaled by sqrt(10*log2(e)) so sim accumulates 10*log2(e)*<a,b>
// and the epilogue is a bare exp2f.
#define PRESCALE 3.798283f

typedef short  bf16x8  __attribute__((ext_vector_type(8)));
typedef float  floatx4 __attribute__((ext_vector_type(4)));

__device__ __forceinline__ unsigned short f2bf_rne(float f) {
    union { float f; unsigned u; } c; c.f = f;
    unsigned u = c.u;
    unsigned r = (u + 0x7fffu + ((u >> 16) & 1u)) >> 16;
    return (unsigned short)r;
}

// ---------------------------------------------------------------------------
// Kernel A: fp32 -> bf16 (RNE) with PRESCALE folded in. First 64 blocks also
// zero the 16384-float accumulator region (replaces a memset dispatch).
// ---------------------------------------------------------------------------
__global__ __launch_bounds__(256) void convert_kernel(
    const float* __restrict__ in, unsigned short* __restrict__ out,
    float* __restrict__ accum /* all_sum ++ pos_sum, 2*NROWS floats */)
{
    int i = (blockIdx.x * 256 + threadIdx.x) * 4;
    float4 v = *(const float4*)(in + i);
    ushort4 o;
    o.x = f2bf_rne(v.x * PRESCALE);
    o.y = f2bf_rne(v.y * PRESCALE);
    o.z = f2bf_rne(v.z * PRESCALE);
    o.w = f2bf_rne(v.w * PRESCALE);
    *(ushort4*)(out + i) = o;
    if (blockIdx.x < (2 * NROWS) / 256)
        accum[blockIdx.x * 256 + threadIdx.x] = 0.0f;
}

// ---------------------------------------------------------------------------
// Kernel B: symmetric-half fused GEMM, register-staged K-loop.
// Staging is global->VGPR->LDS (NOT global_load_lds): the vmcnt wait attaches
// to the ds_write consuming the registers, whose loads were issued a FULL
// iteration earlier (~1 MFMA phase of slack) — so no barrier ever exposes raw
// L2/HBM latency (R3's stall: global_load_lds forces vmcnt(0)-at-barrier with
// zero slack). Raw asm barriers: barrier1 = lgkmcnt(0);s_barrier (ds_writes
// visible), barrier2 = bare s_barrier (reads retired via MFMA issue order).
// Single 32 KB LDS buffer, fully unrolled, static addresses (R5's VGPR bloat
// came from rotating 3-stage indices — avoided here).
// LDS chunk swizzle c' = c ^ (row&7): 0 bank conflicts (measured R3).
// Off-diagonal tiles feed row- AND col-reduces (symmetry); diag masks j==i.
// ---------------------------------------------------------------------------
__global__ __launch_bounds__(256, 3) void gemm_fused_kernel(
    const unsigned short* __restrict__ E,   // bf16 bits (prescaled), [NROWS][DIM]
    const int*            __restrict__ labels,
    float*                __restrict__ all_sum,
    float*                __restrict__ pos_sum)
{
    __shared__ __align__(16) unsigned short sA[BM * BK];   // 16 KB
    __shared__ __align__(16) unsigned short sB[BN * BK];   // 16 KB

    const int tid  = threadIdx.x;
    const int lane = tid & 63;
    const int w    = tid >> 6;
    const int wm   = w >> 1;        // wave row (0..1) -> 64 rows
    const int wn   = w & 1;         // wave col (0..1) -> 64 cols
    const int colw = lane & 15;
    const int quad = lane >> 4;

    // decode lower-triangle pair: t -> (bi, bj), bj <= bi
    const int t = blockIdx.x;
    int bi = (int)((sqrtf(8.0f * (float)t + 1.0f) - 1.0f) * 0.5f);
    while ((bi + 1) * (bi + 2) / 2 <= t) ++bi;
    while (bi * (bi + 1) / 2 > t) --bi;
    const int bj = t - bi * (bi + 1) / 2;

    const int rBase = bi * BM;      // rows (A tile)
    const int cBase = bj * BN;      // cols (B tile)
    const bool diag = (bi == bj);

    // Staging: tile = 128x64 = 1024 chunks of 16B. Thread t owns LDS chunks
    // t, t+256, t+512, t+768 (rows srow + 32j). Swizzled column placement:
    // global chunk c = (t&7) ^ (srow&7); srow&7 invariant under +32.
    const int srow = tid >> 3;
    const int scol = (((tid & 7) ^ (srow & 7)) << 3);  // element col in 0..63
    const int e0   = tid * 8;                          // LDS elem offset chunk0

    floatx4 acc[4][4];
    #pragma unroll
    for (int i = 0; i < 4; ++i)
        #pragma unroll
        for (int j = 0; j < 4; ++j)
            acc[i][j] = (floatx4)0.0f;

    // Fragment reads: row = {wm,wn}*64 + mt*16 + colw; chunk (h*4+quad) stored
    // at slot (h*4+quad) ^ (row&7) = ... ^ (colw&7)  (mt*16, wm*64 drop out).
    const int swz   = colw & 7;
    const int aRow0 = (wm * 64 + colw) * BK;
    const int bRow0 = (wn * 64 + colw) * BK;

    const size_t gA0 = (size_t)(rBase + srow) * DIM + scol;
    const size_t gB0 = (size_t)(cBase + srow) * DIM + scol;
    const size_t rstep = (size_t)32 * DIM;

    // register staging buffers (8 x b128 = 32 VGPRs)
    bf16x8 rA[4], rB[4];

    // prologue: issue loads for k0 = 0
    #pragma unroll
    for (int j = 0; j < 4; ++j) {
        rA[j] = *(const bf16x8*)(E + gA0 + j * rstep);
        rB[j] = *(const bf16x8*)(E + gB0 + j * rstep);
    }

    #pragma unroll
    for (int it = 0; it < NITER; ++it) {
        // regs -> LDS (compiler inserts vmcnt waits here; loads had ~1 full
        // iteration of slack)
        #pragma unroll
        for (int j = 0; j < 4; ++j) {
            *(bf16x8*)&sA[e0 + j * 2048] = rA[j];
            *(bf16x8*)&sB[e0 + j * 2048] = rB[j];
        }
        // issue next iteration's loads; they fly across the barrier + MFMAs
        if (it + 1 < NITER) {
            const size_t kOff = (size_t)(it + 1) * BK;
            #pragma unroll
            for (int j = 0; j < 4; ++j) {
                rA[j] = *(const bf16x8*)(E + gA0 + j * rstep + kOff);
                rB[j] = *(const bf16x8*)(E + gB0 + j * rstep + kOff);
            }
        }
        // barrier1: ds_writes visible to the block; NO vmcnt drain
        asm volatile("s_waitcnt lgkmcnt(0)\n\ts_barrier" ::: "memory");

        #pragma unroll
        for (int h = 0; h < 2; ++h) {
            const int cOff = (((h << 2) | quad) ^ swz) << 3;
            bf16x8 aF[4], bF[4];
            #pragma unroll
            for (int mt = 0; mt < 4; ++mt)
                aF[mt] = *(const bf16x8*)&sA[aRow0 + mt * 16 * BK + cOff];
            #pragma unroll
            for (int nt = 0; nt < 4; ++nt)
                bF[nt] = *(const bf16x8*)&sB[bRow0 + nt * 16 * BK + cOff];

            #pragma unroll
            for (int mt = 0; mt < 4; ++mt)
                #pragma unroll
                for (int nt = 0; nt < 4; ++nt)
                    acc[mt][nt] = __builtin_amdgcn_mfma_f32_16x16x32_bf16(
                        aF[mt], bF[nt], acc[mt][nt], 0, 0, 0);
        }
        // barrier2: all reads of this tile retired (MFMA issue ordering) —
        // safe to overwrite LDS next iteration. Bare barrier, no waitcnt.
        if (it + 1 < NITER)
            asm volatile("s_barrier" ::: "memory");
    }

    // Epilogue. C/D layout (16x16x32): col = lane&15, row = quad*4 + reg.
    float labc[4];
    int   gcol[4];
    #pragma unroll
    for (int nt = 0; nt < 4; ++nt) {
        gcol[nt] = cBase + wn * 64 + nt * 16 + colw;
        labc[nt] = (float)labels[gcol[nt]];
    }

    float colAll[4] = {0.f, 0.f, 0.f, 0.f};
    float colPos[4] = {0.f, 0.f, 0.f, 0.f};

    #pragma unroll
    for (int mt = 0; mt < 4; ++mt) {
        const int growBase = rBase + wm * 64 + mt * 16 + quad * 4;
        #pragma unroll
        for (int r = 0; r < 4; ++r) {
            const int grow = growBase + r;
            const float labr = (float)labels[grow];
            float sAll = 0.f, sPos = 0.f;
            #pragma unroll
            for (int nt = 0; nt < 4; ++nt) {
                float ev = exp2f(acc[mt][nt][r]);   // PRESCALE folded into E
                if (diag && grow == gcol[nt]) ev = 0.0f;  // exclude self
                sAll += ev;
                sPos += ev * labc[nt];
                colAll[nt] += ev;
                colPos[nt] += ev * labr;
            }
            // row-reduce across the 16 lanes (same quad) sharing this row
            #pragma unroll
            for (int off = 1; off < 16; off <<= 1) {
                sAll += __shfl_xor(sAll, off);
                sPos += __shfl_xor(sPos, off);
            }
            if (colw == 0) {
                atomicAdd(&all_sum[grow], sAll);
                atomicAdd(&pos_sum[grow], sPos);
            }
        }
    }

    if (!diag) {
        // col-reduce: sum across quads (lanes differing in bits 4,5)
        #pragma unroll
        for (int nt = 0; nt < 4; ++nt) {
            float a = colAll[nt], p = colPos[nt];
            a += __shfl_xor(a, 16);  p += __shfl_xor(p, 16);
            a += __shfl_xor(a, 32);  p += __shfl_xor(p, 32);
            if (quad == 0) {
                atomicAdd(&all_sum[gcol[nt]], a);
                atomicAdd(&pos_sum[gcol[nt]], p);
            }
        }
    }
}

// ---------------------------------------------------------------------------
// Kernel C: loss = mean over rows with lab==1 of -log(pos/(all+eps)); 0 if n_ref<2
// ---------------------------------------------------------------------------
__global__ __launch_bounds__(1024) void finalize_kernel(
    const float* __restrict__ all_sum,
    const float* __restrict__ pos_sum,
    const int*   __restrict__ labels,
    float*       __restrict__ out)
{
    __shared__ float sSum[1024];
    __shared__ float sCnt[1024];
    const int tid = threadIdx.x;
    float lsum = 0.f, lcnt = 0.f;
    for (int i = tid; i < NROWS; i += 1024) {
        if (labels[i] > 0) {
            float p = pos_sum[i];
            float a = all_sum[i] + EPS;
            lsum += -logf(p / a);
            lcnt += 1.0f;
        }
    }
    sSum[tid] = lsum;
    sCnt[tid] = lcnt;
    __syncthreads();
    for (int s = 512; s > 0; s >>= 1) {
        if (tid < s) { sSum[tid] += sSum[tid + s]; sCnt[tid] += sCnt[tid + s]; }
        __syncthreads();
    }
    if (tid == 0) {
        float n = sCnt[0];
        out[0] = (n < 2.0f) ? 0.0f : sSum[0] / fmaxf(n, 1.0f);
    }
}

// ---------------------------------------------------------------------------
extern "C" void kernel_launch(void* const* d_in, const int* in_sizes, int n_in,
                              void* d_out, int out_size, void* d_ws, size_t ws_size,
                              hipStream_t stream) {
    const float* emb    = (const float*)d_in[0];
    const int*   labels = (const int*)d_in[1];
    float*       out    = (float*)d_out;

    // workspace layout: [bf16 E: 16 MB][all_sum: 32 KB][pos_sum: 32 KB]
    unsigned short* Ebf = (unsigned short*)d_ws;
    const size_t embBytes = (size_t)NROWS * DIM * sizeof(unsigned short);
    float* all_sum = (float*)((char*)d_ws + embBytes);
    float* pos_sum = all_sum + NROWS;

    convert_kernel<<<(NROWS * DIM) / (4 * 256), 256, 0, stream>>>(emb, Ebf, all_sum);

    const int nBlocksTri = (NROWS / BM) * (NROWS / BM + 1) / 2;  // 64*65/2 = 2080
    gemm_fused_kernel<<<nBlocksTri, 256, 0, stream>>>(Ebf, labels, all_sum, pos_sum);

    finalize_kernel<<<1, 1024, 0, stream>>>(all_sum, pos_sum, labels, out);
}